// Round 14
// baseline (292.323 us; speedup 1.0000x reference)
//
#include <hip/hip_runtime.h>
#include <hip/hip_bf16.h>
#include <stdint.h>

// B=512, N=256, D=128, 4 layers. One block (512 thr, 8 waves) per batch.
// ALGORITHM (associativity): R = Attn*key/n = Z * (Qf * G * Pf^T) / n where
//   G = Z^T A Z = sum_{m<256} z_m z_m^T   (129x129 symmetric)
// Gbar = G[0:128,0:128], g = G[0:128,128]:
//   T1 = Gbar*P^T; M0 = Q*T1; m1 = Q*g;  R[:,c<128] = Zc*M0/n; R[:,128] = Zc*m1/n.
// STATE: master Z = bf16-hi in LDS (ZT, transposed [d][tok], pitch 264 with a
// 16B pad every 8 rows) + bf16-lo residual in regs. acc -> GLOBAL scratch
// (bf16-packed uint4, coalesced slot*512+tid) in the first 64 KB of this
// block's own d_out slice (layer 0 never reads it; epilogue overwrites it).
// R14 = R13 (254us) + three latency-path fixes:
//  1) ZT group-pad zto(d)=d*264+(d&~7): the aw-gather reads rows 8 apart at
//     fixed tok; any multiple-of-8 pitch makes the 4 g4-groups collide 4-way
//     (8*ZTP = 0 mod 32 banks). The per-8-row 16B pad shifts groups by 4
//     banks -> conflict-free; G b128 row reads drop to the free 2-way min.
//  2) Barrier A removed (3 barriers/layer): everything it guarded is already
//     ordered by bar E (D-256 no longer writes ZT; g-GEMV reads zbar[0..255]
//     only). A single pre-loop sync covers init.
//  3) gamma vectorized: prep_gt builds transposed gt[l][col][m] (pitch 260)
//     in d_ws (runtime-gated on ws_size; scalar fallback kept) -> 64 scalar
//     gamma loads/thread/layer become 16 float4 loads.

using short8 = __attribute__((ext_vector_type(8))) short;
using f32x4  = __attribute__((ext_vector_type(4))) float;

#define MFMA16(A,B,C) __builtin_amdgcn_mfma_f32_16x16x32_bf16((A),(B),(C),0,0,0)

static __device__ __forceinline__ uint16_t f2bf(float f){
  union{__hip_bfloat16 h;uint16_t u;}c; c.h=__float2bfloat16(f); return c.u; }
static __device__ __forceinline__ uint32_t pk2(float lo,float hi){
  return (uint32_t)f2bf(lo) | ((uint32_t)f2bf(hi)<<16); }
static __device__ __forceinline__ float bfu(uint16_t u){ return __uint_as_float(((uint32_t)u)<<16); }
static __device__ __forceinline__ float bflo(uint32_t p){ return __uint_as_float(p<<16); }
static __device__ __forceinline__ float bfhi(uint32_t p){ return __uint_as_float(p&0xffff0000u); }

union F4 { uint32_t u[4]; short8 s8; };

// ZT element offset (u16 units): row pitch 264 + 16B pad per 8-row group.
static __device__ __forceinline__ int zto(int d){ return d*264 + (d & ~7); }

// ---- LDS geometry ----
#define BUFP  152                           // GbA/GbB pitch (u16): 76 dw = 12 mod 32
#define SCRP  40                            // per-wave scratch pitch (u16)
#define ZT_OFF   0                          // 128*264*2 + 16*16 = 67,840
#define GBA_OFF  67840                      // 128*152*2 = 38,912
#define GBB_OFF  106752                     // 128*152*2 = 38,912
#define SCR_OFF  145664                     // 8*16*40*2 = 10,240
#define ZBAR_OFF 155904                     // 260*4 = 1,040
#define Z256_OFF 156944                     // 128*4 = 512
#define A128_OFF 157456                     // 256*4 = 1,024
#define A256_OFF 158480                     // 132*4 = 528
#define G_OFF    159008                     // 128*4 = 512
#define M1_OFF   159520                     // 128*4 = 512
#define LDS_TOTAL 160032

__global__ __launch_bounds__(512)
__attribute__((amdgpu_waves_per_eu(2, 2)))
void tf_layers(const float* __restrict__ Zin, const float* __restrict__ gamma,
               const uint16_t* __restrict__ Qg, const uint16_t* __restrict__ Pg,
               const float* __restrict__ gt,   // transposed gamma or nullptr
               float* __restrict__ Zout)
{
  extern __shared__ char lds[];
  uint16_t* ZT    = (uint16_t*)(lds + ZT_OFF);   // zto(d)+tok, tok<256
  uint16_t* GbA   = (uint16_t*)(lds + GBA_OFF);  // [128][BUFP]: Gbar
  uint16_t* GbB   = (uint16_t*)(lds + GBB_OFF);  // [128][BUFP]: Mc[c][d]
  float*    zbar  = (float*)(lds + ZBAR_OFF);    // [257] f32 master col 128
  float*    z256f = (float*)(lds + Z256_OFF);    // [128] f32 master row 256
  float*    acc128= (float*)(lds + A128_OFF);    // [256] f32 acc col 128
  float*    acc256= (float*)(lds + A256_OFF);    // [129] f32 acc row 256
  float*    gv    = (float*)(lds + G_OFF);       // [128] g = Gbar[:,128]
  float*    m1v   = (float*)(lds + M1_OFF);      // [128] m1 = Q*g

  const int tid = threadIdx.x, lane = tid & 63, w = tid >> 6;
  const int l15 = lane & 15, g4 = lane >> 4;
  const int b = blockIdx.x;
  const float inv_n = 1.0f/256.0f;

  uint16_t* scr = (uint16_t*)(lds + SCR_OFF) + w * 16 * SCRP;

  const float* Zb = Zin + (size_t)b*33153;   // 257*129
  float*       Zo = Zout + (size_t)b*33153;

  // acc scratch: 16B-aligned, inside this block's own output slice (64 KB).
  uint4* accb = (uint4*)(((uintptr_t)Zo + 15) & ~(uintptr_t)15);

  // ---- init: ZT (transposed bf16 hi, tok<256), zbar, z256f, acc arrays ----
  for (int i2 = tid; i2 < 33153; i2 += 512) {
    int r = i2/129, c = i2 - r*129;
    float v = Zb[i2];
    if (c < 128) { if (r < 256) ZT[zto(c) + r] = f2bf(v); else z256f[c] = v; }
    else zbar[r] = v;
  }
  if (tid < 256) acc128[tid] = 0.0f;
  if (tid < 129) acc256[tid] = 0.0f;

  // lo residual regs for own rows (D-frag layout: row mb+4g4+rr, col 16it+l15)
  uint32_t lopk[2][16];
#pragma unroll
  for (int ti = 0; ti < 2; ++ti) {
    const int mb = 16*w + 128*ti;
#pragma unroll
    for (int it = 0; it < 8; ++it) {
      const float* zp = Zb + (size_t)(mb + 4*g4)*129 + 16*it + l15;
      float v0 = zp[0], v1 = zp[129], v2 = zp[258], v3 = zp[387];
      lopk[ti][2*it]   = pk2(v0 - bfu(f2bf(v0)), v1 - bfu(f2bf(v1)));
      lopk[ti][2*it+1] = pk2(v2 - bfu(f2bf(v2)), v3 - bfu(f2bf(v3)));
    }
  }
  __syncthreads();   // init complete (replaces per-layer bar A)

#pragma unroll 1
  for (int l = 0; l < 4; ++l) {
    const uint16_t* Ql  = Qg + l*16384;
    const uint16_t* Pl  = Pg + l*16384;
    const float*    gml = gamma + l*33153;
    const float*    gtl = gt ? (gt + (size_t)l*129*260) : nullptr;
    const bool last = (l == 3);

    // ===== G: Gbar[i][j] = sum_{m<256} Z[m][i]Z[m][j]; g[i] = sum Z[m][i]zbar[m]
    {
      f32x4 gacc[8];
#pragma unroll
      for (int jt = 0; jt < 8; ++jt) gacc[jt] = (f32x4){0,0,0,0};
#pragma unroll
      for (int mw = 0; mw < 8; ++mw) {
        short8 af = *(const short8*)(ZT + zto(16*w+l15) + 32*mw + 8*g4);
#pragma unroll
        for (int jt = 0; jt < 8; ++jt) {
          short8 bf = *(const short8*)(ZT + zto(16*jt+l15) + 32*mw + 8*g4);
          gacc[jt] = MFMA16(af, bf, gacc[jt]);
        }
      }
      // symmetric write: lane holds G[i=16w+4g4+rr][j=16jt+l15] -> GbA[j][i]
#pragma unroll
      for (int jt = 0; jt < 8; ++jt)
        *(uint2*)(GbA + (16*jt+l15)*BUFP + 16*w + 4*g4) =
            make_uint2(pk2(gacc[jt][0],gacc[jt][1]), pk2(gacc[jt][2],gacc[jt][3]));
      // g GEMV: i = tid>>2; q-interleaved 8-tok blocks (conflict-free), 256 toks
      {
        const int i = tid >> 2, q = lane & 3;
        float s = 0;
#pragma unroll
        for (int jj = 0; jj < 8; ++jj) {
          const int t0 = 8*q + 32*jj;
          uint4 zv = *(const uint4*)(ZT + zto(i) + t0);
          f32x4 z0 = *(const f32x4*)(zbar + t0);
          f32x4 z1 = *(const f32x4*)(zbar + t0 + 4);
          s += bflo(zv.x)*z0[0] + bfhi(zv.x)*z0[1] + bflo(zv.y)*z0[2] + bfhi(zv.y)*z0[3]
             + bflo(zv.z)*z1[0] + bfhi(zv.z)*z1[1] + bflo(zv.w)*z1[2] + bfhi(zv.w)*z1[3];
        }
        s += __shfl_xor(s,1); s += __shfl_xor(s,2);
        if (q == 0) gv[i] = s;
      }
    }
    __syncthreads();   // bar B: Gbar, g ready

    // ===== T1 = Gbar*P^T -> regs (wave w: cols c=16w+l15); m1 = Q*g =====
    uint32_t t1t[16];
    {
      short8 bq[4];
#pragma unroll
      for (int k = 0; k < 4; ++k)
        bq[k] = *(const short8*)(Pl + (16*w+l15)*128 + 32*k + 8*g4);
#pragma unroll
      for (int it = 0; it < 8; ++it) {
        f32x4 d4 = {0,0,0,0};
#pragma unroll
        for (int k = 0; k < 4; ++k) {
          short8 ag = *(const short8*)(GbA + (16*it+l15)*BUFP + 32*k + 8*g4);
          d4 = MFMA16(ag, bq[k], d4);
        }
        t1t[2*it]   = pk2(d4[0], d4[1]);
        t1t[2*it+1] = pk2(d4[2], d4[3]);
      }
      // m1[d] = sum_e Q[d][e] g[e]  (gv reads are broadcast: free)
      {
        const int d = tid >> 2, q = lane & 3;
        float s = 0;
#pragma unroll
        for (int j = 0; j < 4; ++j) {
          short8 qv = *(const short8*)(Ql + d*128 + 32*q + 8*j);
          f32x4 g0 = *(const f32x4*)(gv + 32*q + 8*j);
          f32x4 g1 = *(const f32x4*)(gv + 32*q + 8*j + 4);
          s += bfu((uint16_t)qv[0])*g0[0] + bfu((uint16_t)qv[1])*g0[1]
             + bfu((uint16_t)qv[2])*g0[2] + bfu((uint16_t)qv[3])*g0[3]
             + bfu((uint16_t)qv[4])*g1[0] + bfu((uint16_t)qv[5])*g1[1]
             + bfu((uint16_t)qv[6])*g1[2] + bfu((uint16_t)qv[7])*g1[3];
        }
        s += __shfl_xor(s,1); s += __shfl_xor(s,2);
        if (q == 0) m1v[d] = s;
      }
    }
    // (no barrier: Mc writes GbB, whose last readers finished before bar B)

    // ===== Mc[c][d] = sum_e T1t[c][e] Q[d][e]  (wave w: rows c=16w+l15) =====
    {
      F4 bfr[4];
#pragma unroll
      for (int k2 = 0; k2 < 4; ++k2) {
        *(uint2*)(scr + l15*SCRP + 4*g4)      = make_uint2(t1t[4*k2],   t1t[4*k2+1]);
        *(uint2*)(scr + l15*SCRP + 16 + 4*g4) = make_uint2(t1t[4*k2+2], t1t[4*k2+3]);
        bfr[k2].s8 = *(const short8*)(scr + l15*SCRP + 8*g4);  // same-wave RAW
      }
#pragma unroll
      for (int dt = 0; dt < 8; ++dt) {
        f32x4 d4 = {0,0,0,0};
#pragma unroll
        for (int k2 = 0; k2 < 4; ++k2) {
          short8 aq = *(const short8*)(Ql + (16*dt+l15)*128 + 32*k2 + 8*g4);
          d4 = MFMA16(aq, bfr[k2].s8, d4);
        }
        *(uint2*)(GbB + (16*w+l15)*BUFP + 16*dt + 4*g4) =
            make_uint2(pk2(d4[0],d4[1]), pk2(d4[2],d4[3]));
      }
    }
    __syncthreads();   // bar D: Mc (GbB), m1 ready

    // ===== D-main: R = Z*Mc/n + fused update (own rows); r128; r256 =====
    float r256v = 0.0f, rcv = 0.0f;
#pragma unroll
    for (int ti = 0; ti < 2; ++ti) {
      const int mb = 16*w + 128*ti;
      F4 aw[4];
      float rp = 0;
#pragma unroll
      for (int q = 0; q < 4; ++q) {      // A-frags: Z own rows from ZT columns
        uint16_t ev[8];
#pragma unroll
        for (int j = 0; j < 8; ++j) ev[j] = ZT[zto(32*q + 8*g4 + j) + mb + l15];
        aw[q].u[0] = (uint32_t)ev[0] | ((uint32_t)ev[1]<<16);
        aw[q].u[1] = (uint32_t)ev[2] | ((uint32_t)ev[3]<<16);
        aw[q].u[2] = (uint32_t)ev[4] | ((uint32_t)ev[5]<<16);
        aw[q].u[3] = (uint32_t)ev[6] | ((uint32_t)ev[7]<<16);
        f32x4 m0 = *(const f32x4*)(m1v + 32*q + 8*g4);
        f32x4 m4 = *(const f32x4*)(m1v + 32*q + 8*g4 + 4);
        rp += bfu(ev[0])*m0[0] + bfu(ev[1])*m0[1] + bfu(ev[2])*m0[2] + bfu(ev[3])*m0[3]
            + bfu(ev[4])*m4[0] + bfu(ev[5])*m4[1] + bfu(ev[6])*m4[2] + bfu(ev[7])*m4[3];
      }
      rp += __shfl_xor(rp,16); rp += __shfl_xor(rp,32);
      rp *= inv_n;                       // R[mb+l15][128]
#pragma unroll
      for (int h = 0; h < 2; ++h) {      // col halves
        // scoped acc prefetch: issues before the MFMA cluster, used after
        uint4 q0, q1;
        if (l > 0) {
          q0 = accb[(((ti*2 + h)*2 + 0) << 9) + tid];
          q1 = accb[(((ti*2 + h)*2 + 1) << 9) + tid];
        } else {
          q0 = make_uint4(0,0,0,0); q1 = make_uint4(0,0,0,0);
        }
        f32x4 racc[4];
#pragma unroll
        for (int i = 0; i < 4; ++i) racc[i] = (f32x4){0,0,0,0};
#pragma unroll
        for (int c4 = 0; c4 < 4; ++c4) {
          const int ct = 4*h + c4;
#pragma unroll
          for (int q = 0; q < 4; ++q) {
            short8 bm = *(const short8*)(GbB + (16*ct+l15)*BUFP + 32*q + 8*g4);
            racc[c4] = MFMA16(aw[q].s8, bm, racc[c4]);
          }
        }
        uint32_t ao[8];
        ao[0]=q0.x; ao[1]=q0.y; ao[2]=q0.z; ao[3]=q0.w;
        ao[4]=q1.x; ao[5]=q1.y; ao[6]=q1.z; ao[7]=q1.w;
        uint32_t an[8];
#pragma unroll
        for (int c4 = 0; c4 < 4; ++c4) {
          const int ct = 4*h + c4, col = 16*ct + l15;
          uint16_t* zt = ZT + zto(col) + mb + 4*g4;
          uint2 hold = *(uint2*)zt;
          float ga0, ga1, ga2, ga3;
          if (gtl) {
            f32x4 g4v = *(const f32x4*)(gtl + (size_t)col*260 + mb + 4*g4);
            ga0 = g4v[0]; ga1 = g4v[1]; ga2 = g4v[2]; ga3 = g4v[3];
          } else {
            const float* gp = gml + (size_t)(mb + 4*g4)*129 + col;
            ga0 = gp[0]; ga1 = gp[129]; ga2 = gp[258]; ga3 = gp[387];
          }
          float R0 = racc[c4][0]*inv_n, R1 = racc[c4][1]*inv_n;
          float R2 = racc[c4][2]*inv_n, R3 = racc[c4][3]*inv_n;
          float a0 = bflo(ao[2*c4]),   a1 = bfhi(ao[2*c4]);
          float a2 = bflo(ao[2*c4+1]), a3 = bfhi(ao[2*c4+1]);
          float z0 = bflo(hold.x) + bflo(lopk[ti][2*ct])   + R0 + a0;
          float z1 = bfhi(hold.x) + bfhi(lopk[ti][2*ct])   + R1 + a1;
          float z2 = bflo(hold.y) + bflo(lopk[ti][2*ct+1]) + R2 + a2;
          float z3 = bfhi(hold.y) + bfhi(lopk[ti][2*ct+1]) + R3 + a3;
          an[2*c4]   = pk2(a0 + R0*ga0, a1 + R1*ga1);
          an[2*c4+1] = pk2(a2 + R2*ga2, a3 + R3*ga3);
          uint16_t h0 = f2bf(z0), h1 = f2bf(z1), h2 = f2bf(z2), h3 = f2bf(z3);
          *(uint2*)zt = make_uint2((uint32_t)h0 | ((uint32_t)h1<<16),
                                   (uint32_t)h2 | ((uint32_t)h3<<16));
          lopk[ti][2*ct]   = pk2(z0 - bfu(h0), z1 - bfu(h1));
          lopk[ti][2*ct+1] = pk2(z2 - bfu(h2), z3 - bfu(h3));
        }
        if (!last) {
          accb[(((ti*2 + h)*2 + 0) << 9) + tid] = make_uint4(an[0],an[1],an[2],an[3]);
          accb[(((ti*2 + h)*2 + 1) << 9) + tid] = make_uint4(an[4],an[5],an[6],an[7]);
        }
      }
      if (lane < 16) {                   // col-128 master update (f32 in LDS)
        const int m = mb + l15;
        float zb = zbar[m], a = acc128[m], ga = gml[m*129 + 128];
        float zn = zb + rp + a;
        zbar[m] = zn; acc128[m] = a + rp*ga;
      }
    }
    // r256[c] = sum_{d<128} Z[256][d]*Mc[c][d] — q-interleaved 8-d blocks
    {
      const int c = tid >> 2, q = lane & 3;
      float s = 0;
#pragma unroll
      for (int jj = 0; jj < 4; ++jj) {   // 4 lanes x 4 x 8 = 128 d's
        const int d0 = 8*q + 32*jj;
        uint4 mv = *(const uint4*)(GbB + c*BUFP + d0);
        f32x4 z0 = *(const f32x4*)(z256f + d0);
        f32x4 z1 = *(const f32x4*)(z256f + d0 + 4);
        s += z0[0]*bflo(mv.x) + z0[1]*bfhi(mv.x) + z0[2]*bflo(mv.y) + z0[3]*bfhi(mv.y)
           + z1[0]*bflo(mv.z) + z1[1]*bfhi(mv.z) + z1[2]*bflo(mv.w) + z1[3]*bfhi(mv.w);
      }
      s += __shfl_xor(s,1); s += __shfl_xor(s,2);
      r256v = s;
    }
    if (w == 0) {                        // corner: R[256][128]
      const int d0 = lane*2;
      float s = z256f[d0]*m1v[d0] + z256f[d0+1]*m1v[d0+1];
      s += __shfl_xor(s,1); s += __shfl_xor(s,2); s += __shfl_xor(s,4);
      s += __shfl_xor(s,8); s += __shfl_xor(s,16); s += __shfl_xor(s,32);
      rcv = s;
    }
    __syncthreads();   // bar E: all z256f/GbB/ZT reads done

    // ===== D-256: update row 256 (f32 state only) =====
    if ((lane & 3) == 0) {
      const int c = tid >> 2;
      float R = r256v*inv_n;
      float z = z256f[c], a = acc256[c], ga = gml[256*129 + c];
      float zn = z + R + a;
      z256f[c] = zn; acc256[c] = a + R*ga;
    }
    if (w == 0 && lane == 0) {
      float R = rcv*inv_n;
      float ga = gml[256*129 + 128];
      float zn = zbar[256] + R + acc256[128];
      zbar[256] = zn; acc256[128] = acc256[128] + R*ga;
    }
  }

  // ---- coalesced f32 output from LDS (overwrites acc scratch region too) ----
  __syncthreads();
  for (int i2 = tid; i2 < 33153; i2 += 512) {
    int r = i2/129, c = i2 - r*129;
    float v;
    if (c < 128) v = (r == 256) ? z256f[c] : bfu(ZT[zto(c) + r]);
    else         v = zbar[r];
    Zo[i2] = v;
  }
}

// allparam f32 -> bf16, both row-major: Pg[l][i][j]=P[i][j]; Qg[l][i][j]=Q[i][j].
__global__ void prep_params(const float* __restrict__ ap,
                            uint16_t* __restrict__ qg, uint16_t* __restrict__ pg)
{
  int t = blockIdx.x * 256 + threadIdx.x;   // 0..65535 = (l,i,j)
  int l = t >> 14, rem = t & 16383;
  pg[t] = f2bf(ap[(l*2 + 0)*16384 + rem]);
  qg[t] = f2bf(ap[(l*2 + 1)*16384 + rem]);
}

// gamma transpose: gt[l][c][m] (pitch 260) = gamma[l][m][c]
__global__ void prep_gt(const float* __restrict__ gm, float* __restrict__ gt)
{
  int t = blockIdx.x * 256 + threadIdx.x;
  if (t >= 4*129*257) return;
  int l = t / 33153, rem = t - l*33153;
  int c = rem / 257, m = rem - c*257;
  gt[((size_t)l*129 + c)*260 + m] = gm[(size_t)l*33153 + m*129 + c];
}

extern "C" void kernel_launch(void* const* d_in, const int* in_sizes, int n_in,
                              void* d_out, int out_size, void* d_ws, size_t ws_size,
                              hipStream_t stream)
{
  const float* Z  = (const float*)d_in[0];
  const float* ap = (const float*)d_in[1];
  const float* gm = (const float*)d_in[2];

  uint16_t* qg = (uint16_t*)d_ws;             // 4*128*128 bf16
  uint16_t* pg = qg + 4*128*128;              // 4*128*128 bf16 (256 KiB total)

  const size_t gt_need = 262144 + (size_t)4*129*260*4;   // params + gammaT
  float* gt = (ws_size >= gt_need) ? (float*)((char*)d_ws + 262144) : nullptr;

  (void)hipFuncSetAttribute((const void*)tf_layers,
                            hipFuncAttributeMaxDynamicSharedMemorySize, LDS_TOTAL);

  prep_params<<<256, 256, 0, stream>>>(ap, qg, pg);
  if (gt) prep_gt<<<519, 256, 0, stream>>>(gm, gt);
  tf_layers<<<512, 512, LDS_TOTAL, stream>>>(Z, gm, qg, pg, gt, (float*)d_out);
}

// Round 15
// 267.573 us; speedup vs baseline: 1.0925x; 1.0925x over previous
//
#include <hip/hip_runtime.h>
#include <hip/hip_bf16.h>
#include <stdint.h>

// B=512, N=256, D=128, 4 layers. One block (512 thr, 8 waves) per batch.
// ALGORITHM (associativity): R = Attn*key/n = Z * (Qf * G * Pf^T) / n where
//   G = Z^T A Z = sum_{m<256} z_m z_m^T   (129x129 symmetric)
// Gbar = G[0:128,0:128], g = G[0:128,128]:
//   T1 = Gbar*P^T; M0 = Q*T1; m1 = Q*g;  R[:,c<128] = Zc*M0/n; R[:,128] = Zc*m1/n.
// STATE: master Z = bf16-hi in LDS (ZT, transposed [d][tok], pitch 264,
// tok<256; row-256 in f32 z256f) + bf16-lo residual in regs. acc -> GLOBAL
// scratch (bf16-packed uint4, coalesced slot*512+tid) in the first 64 KB of
// this block's own d_out slice (layer 0 never reads it; epilogue overwrites).
// R15 = R13 (best, 254us) + two zero-register-cost changes:
//  1) bar A removed (3 barriers/layer): all deps it guarded are ordered by
//     bar E + next-layer B/D (D-256 no longer writes ZT since R13). A single
//     pre-loop sync covers init.
//  2) uniform-gamma fast path: prep_params checks gamma==1 (flag in d_ws,
//     init via 4-byte hipMemsetAsync); flag-clear -> uniform branch skips all
//     ~33 scalar gamma loads/thread/layer in the D-main dependent chain.
//     Generic gamma path retained -> correct for arbitrary inputs.
// R14 lesson: gammaT/zto addressing complexity re-triggered spills (+28 MB
// WRITE); keep the D-main body register-minimal.

using short8 = __attribute__((ext_vector_type(8))) short;
using f32x4  = __attribute__((ext_vector_type(4))) float;

#define MFMA16(A,B,C) __builtin_amdgcn_mfma_f32_16x16x32_bf16((A),(B),(C),0,0,0)

static __device__ __forceinline__ uint16_t f2bf(float f){
  union{__hip_bfloat16 h;uint16_t u;}c; c.h=__float2bfloat16(f); return c.u; }
static __device__ __forceinline__ uint32_t pk2(float lo,float hi){
  return (uint32_t)f2bf(lo) | ((uint32_t)f2bf(hi)<<16); }
static __device__ __forceinline__ float bfu(uint16_t u){ return __uint_as_float(((uint32_t)u)<<16); }
static __device__ __forceinline__ float bflo(uint32_t p){ return __uint_as_float(p<<16); }
static __device__ __forceinline__ float bfhi(uint32_t p){ return __uint_as_float(p&0xffff0000u); }

union F4 { uint32_t u[4]; short8 s8; };

// ---- LDS geometry ----
#define ZTP   264                           // ZT pitch (u16): [128][264], tok 0..255
#define BUFP  152                           // GbA/GbB pitch (u16): 76 dw = 12 mod 32
#define SCRP  40                            // per-wave scratch pitch (u16)
#define ZT_OFF   0                          // 128*264*2 = 67,584
#define GBA_OFF  67584                      // 128*152*2 = 38,912
#define GBB_OFF  106496                     // 128*152*2 = 38,912
#define SCR_OFF  145408                     // 8*16*40*2 = 10,240
#define ZBAR_OFF 155648                     // 260*4 = 1,040
#define Z256_OFF 156688                     // 128*4 = 512
#define A128_OFF 157200                     // 256*4 = 1,024
#define A256_OFF 158224                     // 132*4 = 528
#define G_OFF    158752                     // 128*4 = 512
#define M1_OFF   159264                     // 128*4 = 512
#define LDS_TOTAL 159776

__global__ __launch_bounds__(512)
__attribute__((amdgpu_waves_per_eu(2, 2)))
void tf_layers(const float* __restrict__ Zin, const float* __restrict__ gamma,
               const uint16_t* __restrict__ Qg, const uint16_t* __restrict__ Pg,
               const int* __restrict__ gflag,
               float* __restrict__ Zout)
{
  extern __shared__ char lds[];
  uint16_t* ZT    = (uint16_t*)(lds + ZT_OFF);   // [128][ZTP]: ZT[d][tok]=bf16 Z[tok][d]
  uint16_t* GbA   = (uint16_t*)(lds + GBA_OFF);  // [128][BUFP]: Gbar
  uint16_t* GbB   = (uint16_t*)(lds + GBB_OFF);  // [128][BUFP]: Mc[c][d]
  float*    zbar  = (float*)(lds + ZBAR_OFF);    // [257] f32 master col 128
  float*    z256f = (float*)(lds + Z256_OFF);    // [128] f32 master row 256
  float*    acc128= (float*)(lds + A128_OFF);    // [256] f32 acc col 128
  float*    acc256= (float*)(lds + A256_OFF);    // [129] f32 acc row 256
  float*    gv    = (float*)(lds + G_OFF);       // [128] g = Gbar[:,128]
  float*    m1v   = (float*)(lds + M1_OFF);      // [128] m1 = Q*g

  const int tid = threadIdx.x, lane = tid & 63, w = tid >> 6;
  const int l15 = lane & 15, g4 = lane >> 4;
  const int b = blockIdx.x;
  const float inv_n = 1.0f/256.0f;
  const bool gOne = (gflag[0] == 0);   // gamma uniformly 1.0

  uint16_t* scr = (uint16_t*)(lds + SCR_OFF) + w * 16 * SCRP;

  const float* Zb = Zin + (size_t)b*33153;   // 257*129
  float*       Zo = Zout + (size_t)b*33153;

  // acc scratch: 16B-aligned, inside this block's own output slice (64 KB).
  uint4* accb = (uint4*)(((uintptr_t)Zo + 15) & ~(uintptr_t)15);

  // ---- init: ZT (transposed bf16 hi, tok<256), zbar, z256f, acc arrays ----
  for (int i2 = tid; i2 < 33153; i2 += 512) {
    int r = i2/129, c = i2 - r*129;
    float v = Zb[i2];
    if (c < 128) { if (r < 256) ZT[c*ZTP + r] = f2bf(v); else z256f[c] = v; }
    else zbar[r] = v;
  }
  if (tid < 256) acc128[tid] = 0.0f;
  if (tid < 129) acc256[tid] = 0.0f;

  // lo residual regs for own rows (D-frag layout: row mb+4g4+rr, col 16it+l15)
  uint32_t lopk[2][16];
#pragma unroll
  for (int ti = 0; ti < 2; ++ti) {
    const int mb = 16*w + 128*ti;
#pragma unroll
    for (int it = 0; it < 8; ++it) {
      const float* zp = Zb + (size_t)(mb + 4*g4)*129 + 16*it + l15;
      float v0 = zp[0], v1 = zp[129], v2 = zp[258], v3 = zp[387];
      lopk[ti][2*it]   = pk2(v0 - bfu(f2bf(v0)), v1 - bfu(f2bf(v1)));
      lopk[ti][2*it+1] = pk2(v2 - bfu(f2bf(v2)), v3 - bfu(f2bf(v3)));
    }
  }
  __syncthreads();   // init complete (replaces per-layer bar A)

#pragma unroll 1
  for (int l = 0; l < 4; ++l) {
    const uint16_t* Ql  = Qg + l*16384;
    const uint16_t* Pl  = Pg + l*16384;
    const float*    gml = gamma + l*33153;
    const bool last = (l == 3);

    // ===== G: Gbar[i][j] = sum_{m<256} Z[m][i]Z[m][j]; g[i] = sum Z[m][i]zbar[m]
    {
      f32x4 gacc[8];
#pragma unroll
      for (int jt = 0; jt < 8; ++jt) gacc[jt] = (f32x4){0,0,0,0};
#pragma unroll
      for (int mw = 0; mw < 8; ++mw) {
        short8 af = *(const short8*)(ZT + (16*w+l15)*ZTP + 32*mw + 8*g4);
#pragma unroll
        for (int jt = 0; jt < 8; ++jt) {
          short8 bf = *(const short8*)(ZT + (16*jt+l15)*ZTP + 32*mw + 8*g4);
          gacc[jt] = MFMA16(af, bf, gacc[jt]);
        }
      }
      // symmetric write: lane holds G[i=16w+4g4+rr][j=16jt+l15] -> GbA[j][i]
#pragma unroll
      for (int jt = 0; jt < 8; ++jt)
        *(uint2*)(GbA + (16*jt+l15)*BUFP + 16*w + 4*g4) =
            make_uint2(pk2(gacc[jt][0],gacc[jt][1]), pk2(gacc[jt][2],gacc[jt][3]));
      // g GEMV: i = tid>>2; q-interleaved 8-tok blocks (conflict-free), 256 toks
      {
        const int i = tid >> 2, q = lane & 3;
        float s = 0;
#pragma unroll
        for (int jj = 0; jj < 8; ++jj) {
          const int t0 = 8*q + 32*jj;
          uint4 zv = *(const uint4*)(ZT + i*ZTP + t0);
          f32x4 z0 = *(const f32x4*)(zbar + t0);
          f32x4 z1 = *(const f32x4*)(zbar + t0 + 4);
          s += bflo(zv.x)*z0[0] + bfhi(zv.x)*z0[1] + bflo(zv.y)*z0[2] + bfhi(zv.y)*z0[3]
             + bflo(zv.z)*z1[0] + bfhi(zv.z)*z1[1] + bflo(zv.w)*z1[2] + bfhi(zv.w)*z1[3];
        }
        s += __shfl_xor(s,1); s += __shfl_xor(s,2);
        if (q == 0) gv[i] = s;
      }
    }
    __syncthreads();   // bar B: Gbar, g ready

    // ===== T1 = Gbar*P^T -> regs (wave w: cols c=16w+l15); m1 = Q*g =====
    uint32_t t1t[16];
    {
      short8 bq[4];
#pragma unroll
      for (int k = 0; k < 4; ++k)
        bq[k] = *(const short8*)(Pl + (16*w+l15)*128 + 32*k + 8*g4);
#pragma unroll
      for (int it = 0; it < 8; ++it) {
        f32x4 d4 = {0,0,0,0};
#pragma unroll
        for (int k = 0; k < 4; ++k) {
          short8 ag = *(const short8*)(GbA + (16*it+l15)*BUFP + 32*k + 8*g4);
          d4 = MFMA16(ag, bq[k], d4);
        }
        t1t[2*it]   = pk2(d4[0], d4[1]);
        t1t[2*it+1] = pk2(d4[2], d4[3]);
      }
      // m1[d] = sum_e Q[d][e] g[e]  (gv reads are broadcast: free)
      {
        const int d = tid >> 2, q = lane & 3;
        float s = 0;
#pragma unroll
        for (int j = 0; j < 4; ++j) {
          short8 qv = *(const short8*)(Ql + d*128 + 32*q + 8*j);
          f32x4 g0 = *(const f32x4*)(gv + 32*q + 8*j);
          f32x4 g1 = *(const f32x4*)(gv + 32*q + 8*j + 4);
          s += bfu((uint16_t)qv[0])*g0[0] + bfu((uint16_t)qv[1])*g0[1]
             + bfu((uint16_t)qv[2])*g0[2] + bfu((uint16_t)qv[3])*g0[3]
             + bfu((uint16_t)qv[4])*g1[0] + bfu((uint16_t)qv[5])*g1[1]
             + bfu((uint16_t)qv[6])*g1[2] + bfu((uint16_t)qv[7])*g1[3];
        }
        s += __shfl_xor(s,1); s += __shfl_xor(s,2);
        if (q == 0) m1v[d] = s;
      }
    }
    // (no barrier: Mc writes GbB, whose last readers finished before bar B)

    // ===== Mc[c][d] = sum_e T1t[c][e] Q[d][e]  (wave w: rows c=16w+l15) =====
    {
      F4 bfr[4];
#pragma unroll
      for (int k2 = 0; k2 < 4; ++k2) {
        *(uint2*)(scr + l15*SCRP + 4*g4)      = make_uint2(t1t[4*k2],   t1t[4*k2+1]);
        *(uint2*)(scr + l15*SCRP + 16 + 4*g4) = make_uint2(t1t[4*k2+2], t1t[4*k2+3]);
        bfr[k2].s8 = *(const short8*)(scr + l15*SCRP + 8*g4);  // same-wave RAW
      }
#pragma unroll
      for (int dt = 0; dt < 8; ++dt) {
        f32x4 d4 = {0,0,0,0};
#pragma unroll
        for (int k2 = 0; k2 < 4; ++k2) {
          short8 aq = *(const short8*)(Ql + (16*dt+l15)*128 + 32*k2 + 8*g4);
          d4 = MFMA16(aq, bfr[k2].s8, d4);
        }
        *(uint2*)(GbB + (16*w+l15)*BUFP + 16*dt + 4*g4) =
            make_uint2(pk2(d4[0],d4[1]), pk2(d4[2],d4[3]));
      }
    }
    __syncthreads();   // bar D: Mc (GbB), m1 ready

    // ===== D-main: R = Z*Mc/n + fused update (own rows); r128; r256 =====
    float r256v = 0.0f, rcv = 0.0f;
#pragma unroll
    for (int ti = 0; ti < 2; ++ti) {
      const int mb = 16*w + 128*ti;
      F4 aw[4];
      float rp = 0;
#pragma unroll
      for (int q = 0; q < 4; ++q) {      // A-frags: Z own rows from ZT columns
        uint16_t ev[8];
#pragma unroll
        for (int j = 0; j < 8; ++j) ev[j] = ZT[(32*q + 8*g4 + j)*ZTP + mb + l15];
        aw[q].u[0] = (uint32_t)ev[0] | ((uint32_t)ev[1]<<16);
        aw[q].u[1] = (uint32_t)ev[2] | ((uint32_t)ev[3]<<16);
        aw[q].u[2] = (uint32_t)ev[4] | ((uint32_t)ev[5]<<16);
        aw[q].u[3] = (uint32_t)ev[6] | ((uint32_t)ev[7]<<16);
        f32x4 m0 = *(const f32x4*)(m1v + 32*q + 8*g4);
        f32x4 m4 = *(const f32x4*)(m1v + 32*q + 8*g4 + 4);
        rp += bfu(ev[0])*m0[0] + bfu(ev[1])*m0[1] + bfu(ev[2])*m0[2] + bfu(ev[3])*m0[3]
            + bfu(ev[4])*m4[0] + bfu(ev[5])*m4[1] + bfu(ev[6])*m4[2] + bfu(ev[7])*m4[3];
      }
      rp += __shfl_xor(rp,16); rp += __shfl_xor(rp,32);
      rp *= inv_n;                       // R[mb+l15][128]
#pragma unroll
      for (int h = 0; h < 2; ++h) {      // col halves
        // scoped acc prefetch: issues before the MFMA cluster, used after
        uint4 q0, q1;
        if (l > 0) {
          q0 = accb[(((ti*2 + h)*2 + 0) << 9) + tid];
          q1 = accb[(((ti*2 + h)*2 + 1) << 9) + tid];
        } else {
          q0 = make_uint4(0,0,0,0); q1 = make_uint4(0,0,0,0);
        }
        f32x4 racc[4];
#pragma unroll
        for (int i = 0; i < 4; ++i) racc[i] = (f32x4){0,0,0,0};
#pragma unroll
        for (int c4 = 0; c4 < 4; ++c4) {
          const int ct = 4*h + c4;
#pragma unroll
          for (int q = 0; q < 4; ++q) {
            short8 bm = *(const short8*)(GbB + (16*ct+l15)*BUFP + 32*q + 8*g4);
            racc[c4] = MFMA16(aw[q].s8, bm, racc[c4]);
          }
        }
        uint32_t ao[8];
        ao[0]=q0.x; ao[1]=q0.y; ao[2]=q0.z; ao[3]=q0.w;
        ao[4]=q1.x; ao[5]=q1.y; ao[6]=q1.z; ao[7]=q1.w;
        uint32_t an[8];
#pragma unroll
        for (int c4 = 0; c4 < 4; ++c4) {
          const int ct = 4*h + c4, col = 16*ct + l15;
          uint16_t* zt = ZT + col*ZTP + mb + 4*g4;
          uint2 hold = *(uint2*)zt;
          float ga0, ga1, ga2, ga3;
          if (gOne) {
            ga0 = ga1 = ga2 = ga3 = 1.0f;
          } else {
            const float* gp = gml + (size_t)(mb + 4*g4)*129 + col;
            ga0 = gp[0]; ga1 = gp[129]; ga2 = gp[258]; ga3 = gp[387];
          }
          float R0 = racc[c4][0]*inv_n, R1 = racc[c4][1]*inv_n;
          float R2 = racc[c4][2]*inv_n, R3 = racc[c4][3]*inv_n;
          float a0 = bflo(ao[2*c4]),   a1 = bfhi(ao[2*c4]);
          float a2 = bflo(ao[2*c4+1]), a3 = bfhi(ao[2*c4+1]);
          float z0 = bflo(hold.x) + bflo(lopk[ti][2*ct])   + R0 + a0;
          float z1 = bfhi(hold.x) + bfhi(lopk[ti][2*ct])   + R1 + a1;
          float z2 = bflo(hold.y) + bflo(lopk[ti][2*ct+1]) + R2 + a2;
          float z3 = bfhi(hold.y) + bfhi(lopk[ti][2*ct+1]) + R3 + a3;
          an[2*c4]   = pk2(a0 + R0*ga0, a1 + R1*ga1);
          an[2*c4+1] = pk2(a2 + R2*ga2, a3 + R3*ga3);
          uint16_t h0 = f2bf(z0), h1 = f2bf(z1), h2 = f2bf(z2), h3 = f2bf(z3);
          *(uint2*)zt = make_uint2((uint32_t)h0 | ((uint32_t)h1<<16),
                                   (uint32_t)h2 | ((uint32_t)h3<<16));
          lopk[ti][2*ct]   = pk2(z0 - bfu(h0), z1 - bfu(h1));
          lopk[ti][2*ct+1] = pk2(z2 - bfu(h2), z3 - bfu(h3));
        }
        if (!last) {
          accb[(((ti*2 + h)*2 + 0) << 9) + tid] = make_uint4(an[0],an[1],an[2],an[3]);
          accb[(((ti*2 + h)*2 + 1) << 9) + tid] = make_uint4(an[4],an[5],an[6],an[7]);
        }
      }
      if (lane < 16) {                   // col-128 master update (f32 in LDS)
        const int m = mb + l15;
        float zb = zbar[m], a = acc128[m];
        float ga = gOne ? 1.0f : gml[m*129 + 128];
        float zn = zb + rp + a;
        zbar[m] = zn; acc128[m] = a + rp*ga;
      }
    }
    // r256[c] = sum_{d<128} Z[256][d]*Mc[c][d] — q-interleaved 8-d blocks
    {
      const int c = tid >> 2, q = lane & 3;
      float s = 0;
#pragma unroll
      for (int jj = 0; jj < 4; ++jj) {   // 4 lanes x 4 x 8 = 128 d's
        const int d0 = 8*q + 32*jj;
        uint4 mv = *(const uint4*)(GbB + c*BUFP + d0);
        f32x4 z0 = *(const f32x4*)(z256f + d0);
        f32x4 z1 = *(const f32x4*)(z256f + d0 + 4);
        s += z0[0]*bflo(mv.x) + z0[1]*bfhi(mv.x) + z0[2]*bflo(mv.y) + z0[3]*bfhi(mv.y)
           + z1[0]*bflo(mv.z) + z1[1]*bfhi(mv.z) + z1[2]*bflo(mv.w) + z1[3]*bfhi(mv.w);
      }
      s += __shfl_xor(s,1); s += __shfl_xor(s,2);
      r256v = s;
    }
    if (w == 0) {                        // corner: R[256][128]
      const int d0 = lane*2;
      float s = z256f[d0]*m1v[d0] + z256f[d0+1]*m1v[d0+1];
      s += __shfl_xor(s,1); s += __shfl_xor(s,2); s += __shfl_xor(s,4);
      s += __shfl_xor(s,8); s += __shfl_xor(s,16); s += __shfl_xor(s,32);
      rcv = s;
    }
    __syncthreads();   // bar E: all z256f/GbB/ZT reads done

    // ===== D-256: update row 256 (f32 state only) =====
    if ((lane & 3) == 0) {
      const int c = tid >> 2;
      float R = r256v*inv_n;
      float z = z256f[c], a = acc256[c];
      float ga = gOne ? 1.0f : gml[256*129 + c];
      float zn = z + R + a;
      z256f[c] = zn; acc256[c] = a + R*ga;
    }
    if (w == 0 && lane == 0) {
      float R = rcv*inv_n;
      float ga = gOne ? 1.0f : gml[256*129 + 128];
      float zn = zbar[256] + R + acc256[128];
      zbar[256] = zn; acc256[128] = acc256[128] + R*ga;
    }
  }

  // ---- coalesced f32 output from LDS (overwrites acc scratch region too) ----
  __syncthreads();
  for (int i2 = tid; i2 < 33153; i2 += 512) {
    int r = i2/129, c = i2 - r*129;
    float v;
    if (c < 128) v = (r == 256) ? z256f[c] : bfu(ZT[c*ZTP + r]);
    else         v = zbar[r];
    Zo[i2] = v;
  }
}

// allparam f32 -> bf16 (row-major), plus gamma==1 uniformity check.
__global__ void prep_params(const float* __restrict__ ap,
                            uint16_t* __restrict__ qg, uint16_t* __restrict__ pg,
                            const float* __restrict__ gm, int* __restrict__ gflag)
{
  int t = blockIdx.x * 256 + threadIdx.x;   // 0..65535 = (l,i,j)
  int l = t >> 14, rem = t & 16383;
  pg[t] = f2bf(ap[(l*2 + 0)*16384 + rem]);
  qg[t] = f2bf(ap[(l*2 + 1)*16384 + rem]);
  // gamma uniformity: 4*257*129 = 132,612 elements, <=3 per thread
  bool bad = false;
  for (int u = t; u < 132612; u += 65536)
    if (gm[u] != 1.0f) { bad = true; break; }
  if (bad) atomicExch(gflag, 1);
}

extern "C" void kernel_launch(void* const* d_in, const int* in_sizes, int n_in,
                              void* d_out, int out_size, void* d_ws, size_t ws_size,
                              hipStream_t stream)
{
  const float* Z  = (const float*)d_in[0];
  const float* ap = (const float*)d_in[1];
  const float* gm = (const float*)d_in[2];

  uint16_t* qg = (uint16_t*)d_ws;             // 4*128*128 bf16
  uint16_t* pg = qg + 4*128*128;              // 4*128*128 bf16 (256 KiB total)
  int* gflag   = (int*)((char*)d_ws + 262144);

  (void)hipFuncSetAttribute((const void*)tf_layers,
                            hipFuncAttributeMaxDynamicSharedMemorySize, LDS_TOTAL);

  (void)hipMemsetAsync(gflag, 0, 4, stream);
  prep_params<<<256, 256, 0, stream>>>(ap, qg, pg, gm, gflag);
  tf_layers<<<512, 512, LDS_TOTAL, stream>>>(Z, gm, qg, pg, gflag, (float*)d_out);
}

// Round 16
// 250.844 us; speedup vs baseline: 1.1654x; 1.0667x over previous
//
#include <hip/hip_runtime.h>
#include <hip/hip_bf16.h>
#include <stdint.h>

// B=512, N=256, D=128, 4 layers. One block (512 thr, 8 waves) per batch.
// ALGORITHM (associativity): R = Attn*key/n = Z * (Qf * G * Pf^T) / n where
//   G = Z^T A Z = sum_{m<256} z_m z_m^T   (129x129 symmetric)
// Gbar = G[0:128,0:128], g = G[0:128,128]:
//   T1 = Gbar*P^T; M0 = Q*T1; m1 = Q*g;  R[:,c<128] = Zc*M0/n; R[:,128] = Zc*m1/n.
// STATE: master Z = bf16-hi in LDS (ZT, transposed [d][tok], pitch 264,
// tok<256; row-256 in f32 z256f) + bf16-lo residual in regs. acc -> GLOBAL
// scratch (bf16-packed uint4, coalesced slot*512+tid) in the first 64 KB of
// this block's own d_out slice (layer 0 never reads it; epilogue overwrites).
// R16 = R13 (best, 254us) + ONLY bar-A removal (3 barriers/layer):
//   audit: D-main ZT/zbar/acc128 writes precede bar E; D-256 writes only
//   z256f/acc256/zbar[256], none read by next layer's G before bar B/D;
//   GbA/GbB ping-pong readers are >=2 barriers away. Pure deletion, zero
//   register cost. (R15 bundled this with a gOne branch in the D-main body
//   which re-triggered spills (+27 MB WRITE) and masked the barrier win --
//   third confirmation that the D-main body tolerates zero added state.)

using short8 = __attribute__((ext_vector_type(8))) short;
using f32x4  = __attribute__((ext_vector_type(4))) float;

#define MFMA16(A,B,C) __builtin_amdgcn_mfma_f32_16x16x32_bf16((A),(B),(C),0,0,0)

static __device__ __forceinline__ uint16_t f2bf(float f){
  union{__hip_bfloat16 h;uint16_t u;}c; c.h=__float2bfloat16(f); return c.u; }
static __device__ __forceinline__ uint32_t pk2(float lo,float hi){
  return (uint32_t)f2bf(lo) | ((uint32_t)f2bf(hi)<<16); }
static __device__ __forceinline__ float bfu(uint16_t u){ return __uint_as_float(((uint32_t)u)<<16); }
static __device__ __forceinline__ float bflo(uint32_t p){ return __uint_as_float(p<<16); }
static __device__ __forceinline__ float bfhi(uint32_t p){ return __uint_as_float(p&0xffff0000u); }

union F4 { uint32_t u[4]; short8 s8; };

// ---- LDS geometry ----
#define ZTP   264                           // ZT pitch (u16): [128][264], tok 0..255
#define BUFP  152                           // GbA/GbB pitch (u16): 76 dw = 12 mod 32
#define SCRP  40                            // per-wave scratch pitch (u16)
#define ZT_OFF   0                          // 128*264*2 = 67,584
#define GBA_OFF  67584                      // 128*152*2 = 38,912
#define GBB_OFF  106496                     // 128*152*2 = 38,912
#define SCR_OFF  145408                     // 8*16*40*2 = 10,240
#define ZBAR_OFF 155648                     // 260*4 = 1,040
#define Z256_OFF 156688                     // 128*4 = 512
#define A128_OFF 157200                     // 256*4 = 1,024
#define A256_OFF 158224                     // 132*4 = 528
#define G_OFF    158752                     // 128*4 = 512
#define M1_OFF   159264                     // 128*4 = 512
#define LDS_TOTAL 159776

__global__ __launch_bounds__(512)
__attribute__((amdgpu_waves_per_eu(2, 2)))
void tf_layers(const float* __restrict__ Zin, const float* __restrict__ gamma,
               const uint16_t* __restrict__ Qg, const uint16_t* __restrict__ Pg,
               float* __restrict__ Zout)
{
  extern __shared__ char lds[];
  uint16_t* ZT    = (uint16_t*)(lds + ZT_OFF);   // [128][ZTP]: ZT[d][tok]=bf16 Z[tok][d]
  uint16_t* GbA   = (uint16_t*)(lds + GBA_OFF);  // [128][BUFP]: Gbar
  uint16_t* GbB   = (uint16_t*)(lds + GBB_OFF);  // [128][BUFP]: Mc[c][d]
  float*    zbar  = (float*)(lds + ZBAR_OFF);    // [257] f32 master col 128
  float*    z256f = (float*)(lds + Z256_OFF);    // [128] f32 master row 256
  float*    acc128= (float*)(lds + A128_OFF);    // [256] f32 acc col 128
  float*    acc256= (float*)(lds + A256_OFF);    // [129] f32 acc row 256
  float*    gv    = (float*)(lds + G_OFF);       // [128] g = Gbar[:,128]
  float*    m1v   = (float*)(lds + M1_OFF);      // [128] m1 = Q*g

  const int tid = threadIdx.x, lane = tid & 63, w = tid >> 6;
  const int l15 = lane & 15, g4 = lane >> 4;
  const int b = blockIdx.x;
  const float inv_n = 1.0f/256.0f;

  uint16_t* scr = (uint16_t*)(lds + SCR_OFF) + w * 16 * SCRP;

  const float* Zb = Zin + (size_t)b*33153;   // 257*129
  float*       Zo = Zout + (size_t)b*33153;

  // acc scratch: 16B-aligned, inside this block's own output slice (64 KB).
  uint4* accb = (uint4*)(((uintptr_t)Zo + 15) & ~(uintptr_t)15);

  // ---- init: ZT (transposed bf16 hi, tok<256), zbar, z256f, acc arrays ----
  for (int i2 = tid; i2 < 33153; i2 += 512) {
    int r = i2/129, c = i2 - r*129;
    float v = Zb[i2];
    if (c < 128) { if (r < 256) ZT[c*ZTP + r] = f2bf(v); else z256f[c] = v; }
    else zbar[r] = v;
  }
  if (tid < 256) acc128[tid] = 0.0f;
  if (tid < 129) acc256[tid] = 0.0f;

  // lo residual regs for own rows (D-frag layout: row mb+4g4+rr, col 16it+l15)
  uint32_t lopk[2][16];
#pragma unroll
  for (int ti = 0; ti < 2; ++ti) {
    const int mb = 16*w + 128*ti;
#pragma unroll
    for (int it = 0; it < 8; ++it) {
      const float* zp = Zb + (size_t)(mb + 4*g4)*129 + 16*it + l15;
      float v0 = zp[0], v1 = zp[129], v2 = zp[258], v3 = zp[387];
      lopk[ti][2*it]   = pk2(v0 - bfu(f2bf(v0)), v1 - bfu(f2bf(v1)));
      lopk[ti][2*it+1] = pk2(v2 - bfu(f2bf(v2)), v3 - bfu(f2bf(v3)));
    }
  }
  __syncthreads();   // init complete (replaces per-layer bar A)

#pragma unroll 1
  for (int l = 0; l < 4; ++l) {
    const uint16_t* Ql  = Qg + l*16384;
    const uint16_t* Pl  = Pg + l*16384;
    const float*    gml = gamma + l*33153;
    const bool last = (l == 3);

    // ===== G: Gbar[i][j] = sum_{m<256} Z[m][i]Z[m][j]; g[i] = sum Z[m][i]zbar[m]
    {
      f32x4 gacc[8];
#pragma unroll
      for (int jt = 0; jt < 8; ++jt) gacc[jt] = (f32x4){0,0,0,0};
#pragma unroll
      for (int mw = 0; mw < 8; ++mw) {
        short8 af = *(const short8*)(ZT + (16*w+l15)*ZTP + 32*mw + 8*g4);
#pragma unroll
        for (int jt = 0; jt < 8; ++jt) {
          short8 bf = *(const short8*)(ZT + (16*jt+l15)*ZTP + 32*mw + 8*g4);
          gacc[jt] = MFMA16(af, bf, gacc[jt]);
        }
      }
      // symmetric write: lane holds G[i=16w+4g4+rr][j=16jt+l15] -> GbA[j][i]
#pragma unroll
      for (int jt = 0; jt < 8; ++jt)
        *(uint2*)(GbA + (16*jt+l15)*BUFP + 16*w + 4*g4) =
            make_uint2(pk2(gacc[jt][0],gacc[jt][1]), pk2(gacc[jt][2],gacc[jt][3]));
      // g GEMV: i = tid>>2; q-interleaved 8-tok blocks (conflict-free), 256 toks
      {
        const int i = tid >> 2, q = lane & 3;
        float s = 0;
#pragma unroll
        for (int jj = 0; jj < 8; ++jj) {
          const int t0 = 8*q + 32*jj;
          uint4 zv = *(const uint4*)(ZT + i*ZTP + t0);
          f32x4 z0 = *(const f32x4*)(zbar + t0);
          f32x4 z1 = *(const f32x4*)(zbar + t0 + 4);
          s += bflo(zv.x)*z0[0] + bfhi(zv.x)*z0[1] + bflo(zv.y)*z0[2] + bfhi(zv.y)*z0[3]
             + bflo(zv.z)*z1[0] + bfhi(zv.z)*z1[1] + bflo(zv.w)*z1[2] + bfhi(zv.w)*z1[3];
        }
        s += __shfl_xor(s,1); s += __shfl_xor(s,2);
        if (q == 0) gv[i] = s;
      }
    }
    __syncthreads();   // bar B: Gbar, g ready

    // ===== T1 = Gbar*P^T -> regs (wave w: cols c=16w+l15); m1 = Q*g =====
    uint32_t t1t[16];
    {
      short8 bq[4];
#pragma unroll
      for (int k = 0; k < 4; ++k)
        bq[k] = *(const short8*)(Pl + (16*w+l15)*128 + 32*k + 8*g4);
#pragma unroll
      for (int it = 0; it < 8; ++it) {
        f32x4 d4 = {0,0,0,0};
#pragma unroll
        for (int k = 0; k < 4; ++k) {
          short8 ag = *(const short8*)(GbA + (16*it+l15)*BUFP + 32*k + 8*g4);
          d4 = MFMA16(ag, bq[k], d4);
        }
        t1t[2*it]   = pk2(d4[0], d4[1]);
        t1t[2*it+1] = pk2(d4[2], d4[3]);
      }
      // m1[d] = sum_e Q[d][e] g[e]  (gv reads are broadcast: free)
      {
        const int d = tid >> 2, q = lane & 3;
        float s = 0;
#pragma unroll
        for (int j = 0; j < 4; ++j) {
          short8 qv = *(const short8*)(Ql + d*128 + 32*q + 8*j);
          f32x4 g0 = *(const f32x4*)(gv + 32*q + 8*j);
          f32x4 g1 = *(const f32x4*)(gv + 32*q + 8*j + 4);
          s += bfu((uint16_t)qv[0])*g0[0] + bfu((uint16_t)qv[1])*g0[1]
             + bfu((uint16_t)qv[2])*g0[2] + bfu((uint16_t)qv[3])*g0[3]
             + bfu((uint16_t)qv[4])*g1[0] + bfu((uint16_t)qv[5])*g1[1]
             + bfu((uint16_t)qv[6])*g1[2] + bfu((uint16_t)qv[7])*g1[3];
        }
        s += __shfl_xor(s,1); s += __shfl_xor(s,2);
        if (q == 0) m1v[d] = s;
      }
    }
    // (no barrier: Mc writes GbB, whose last readers finished before bar B)

    // ===== Mc[c][d] = sum_e T1t[c][e] Q[d][e]  (wave w: rows c=16w+l15) =====
    {
      F4 bfr[4];
#pragma unroll
      for (int k2 = 0; k2 < 4; ++k2) {
        *(uint2*)(scr + l15*SCRP + 4*g4)      = make_uint2(t1t[4*k2],   t1t[4*k2+1]);
        *(uint2*)(scr + l15*SCRP + 16 + 4*g4) = make_uint2(t1t[4*k2+2], t1t[4*k2+3]);
        bfr[k2].s8 = *(const short8*)(scr + l15*SCRP + 8*g4);  // same-wave RAW
      }
#pragma unroll
      for (int dt = 0; dt < 8; ++dt) {
        f32x4 d4 = {0,0,0,0};
#pragma unroll
        for (int k2 = 0; k2 < 4; ++k2) {
          short8 aq = *(const short8*)(Ql + (16*dt+l15)*128 + 32*k2 + 8*g4);
          d4 = MFMA16(aq, bfr[k2].s8, d4);
        }
        *(uint2*)(GbB + (16*w+l15)*BUFP + 16*dt + 4*g4) =
            make_uint2(pk2(d4[0],d4[1]), pk2(d4[2],d4[3]));
      }
    }
    __syncthreads();   // bar D: Mc (GbB), m1 ready

    // ===== D-main: R = Z*Mc/n + fused update (own rows); r128; r256 =====
    float r256v = 0.0f, rcv = 0.0f;
#pragma unroll
    for (int ti = 0; ti < 2; ++ti) {
      const int mb = 16*w + 128*ti;
      F4 aw[4];
      float rp = 0;
#pragma unroll
      for (int q = 0; q < 4; ++q) {      // A-frags: Z own rows from ZT columns
        uint16_t ev[8];
#pragma unroll
        for (int j = 0; j < 8; ++j) ev[j] = ZT[(32*q + 8*g4 + j)*ZTP + mb + l15];
        aw[q].u[0] = (uint32_t)ev[0] | ((uint32_t)ev[1]<<16);
        aw[q].u[1] = (uint32_t)ev[2] | ((uint32_t)ev[3]<<16);
        aw[q].u[2] = (uint32_t)ev[4] | ((uint32_t)ev[5]<<16);
        aw[q].u[3] = (uint32_t)ev[6] | ((uint32_t)ev[7]<<16);
        f32x4 m0 = *(const f32x4*)(m1v + 32*q + 8*g4);
        f32x4 m4 = *(const f32x4*)(m1v + 32*q + 8*g4 + 4);
        rp += bfu(ev[0])*m0[0] + bfu(ev[1])*m0[1] + bfu(ev[2])*m0[2] + bfu(ev[3])*m0[3]
            + bfu(ev[4])*m4[0] + bfu(ev[5])*m4[1] + bfu(ev[6])*m4[2] + bfu(ev[7])*m4[3];
      }
      rp += __shfl_xor(rp,16); rp += __shfl_xor(rp,32);
      rp *= inv_n;                       // R[mb+l15][128]
#pragma unroll
      for (int h = 0; h < 2; ++h) {      // col halves
        // scoped acc prefetch: issues before the MFMA cluster, used after
        uint4 q0, q1;
        if (l > 0) {
          q0 = accb[(((ti*2 + h)*2 + 0) << 9) + tid];
          q1 = accb[(((ti*2 + h)*2 + 1) << 9) + tid];
        } else {
          q0 = make_uint4(0,0,0,0); q1 = make_uint4(0,0,0,0);
        }
        f32x4 racc[4];
#pragma unroll
        for (int i = 0; i < 4; ++i) racc[i] = (f32x4){0,0,0,0};
#pragma unroll
        for (int c4 = 0; c4 < 4; ++c4) {
          const int ct = 4*h + c4;
#pragma unroll
          for (int q = 0; q < 4; ++q) {
            short8 bm = *(const short8*)(GbB + (16*ct+l15)*BUFP + 32*q + 8*g4);
            racc[c4] = MFMA16(aw[q].s8, bm, racc[c4]);
          }
        }
        uint32_t ao[8];
        ao[0]=q0.x; ao[1]=q0.y; ao[2]=q0.z; ao[3]=q0.w;
        ao[4]=q1.x; ao[5]=q1.y; ao[6]=q1.z; ao[7]=q1.w;
        uint32_t an[8];
#pragma unroll
        for (int c4 = 0; c4 < 4; ++c4) {
          const int ct = 4*h + c4, col = 16*ct + l15;
          uint16_t* zt = ZT + col*ZTP + mb + 4*g4;
          uint2 hold = *(uint2*)zt;
          const float* gp = gml + (size_t)(mb + 4*g4)*129 + col;
          float R0 = racc[c4][0]*inv_n, R1 = racc[c4][1]*inv_n;
          float R2 = racc[c4][2]*inv_n, R3 = racc[c4][3]*inv_n;
          float a0 = bflo(ao[2*c4]),   a1 = bfhi(ao[2*c4]);
          float a2 = bflo(ao[2*c4+1]), a3 = bfhi(ao[2*c4+1]);
          float z0 = bflo(hold.x) + bflo(lopk[ti][2*ct])   + R0 + a0;
          float z1 = bfhi(hold.x) + bfhi(lopk[ti][2*ct])   + R1 + a1;
          float z2 = bflo(hold.y) + bflo(lopk[ti][2*ct+1]) + R2 + a2;
          float z3 = bfhi(hold.y) + bfhi(lopk[ti][2*ct+1]) + R3 + a3;
          an[2*c4]   = pk2(a0 + R0*gp[0],   a1 + R1*gp[129]);
          an[2*c4+1] = pk2(a2 + R2*gp[258], a3 + R3*gp[387]);
          uint16_t h0 = f2bf(z0), h1 = f2bf(z1), h2 = f2bf(z2), h3 = f2bf(z3);
          *(uint2*)zt = make_uint2((uint32_t)h0 | ((uint32_t)h1<<16),
                                   (uint32_t)h2 | ((uint32_t)h3<<16));
          lopk[ti][2*ct]   = pk2(z0 - bfu(h0), z1 - bfu(h1));
          lopk[ti][2*ct+1] = pk2(z2 - bfu(h2), z3 - bfu(h3));
        }
        if (!last) {
          accb[(((ti*2 + h)*2 + 0) << 9) + tid] = make_uint4(an[0],an[1],an[2],an[3]);
          accb[(((ti*2 + h)*2 + 1) << 9) + tid] = make_uint4(an[4],an[5],an[6],an[7]);
        }
      }
      if (lane < 16) {                   // col-128 master update (f32 in LDS)
        const int m = mb + l15;
        float zb = zbar[m], a = acc128[m], ga = gml[m*129 + 128];
        float zn = zb + rp + a;
        zbar[m] = zn; acc128[m] = a + rp*ga;
      }
    }
    // r256[c] = sum_{d<128} Z[256][d]*Mc[c][d] — q-interleaved 8-d blocks
    {
      const int c = tid >> 2, q = lane & 3;
      float s = 0;
#pragma unroll
      for (int jj = 0; jj < 4; ++jj) {   // 4 lanes x 4 x 8 = 128 d's
        const int d0 = 8*q + 32*jj;
        uint4 mv = *(const uint4*)(GbB + c*BUFP + d0);
        f32x4 z0 = *(const f32x4*)(z256f + d0);
        f32x4 z1 = *(const f32x4*)(z256f + d0 + 4);
        s += z0[0]*bflo(mv.x) + z0[1]*bfhi(mv.x) + z0[2]*bflo(mv.y) + z0[3]*bfhi(mv.y)
           + z1[0]*bflo(mv.z) + z1[1]*bfhi(mv.z) + z1[2]*bflo(mv.w) + z1[3]*bfhi(mv.w);
      }
      s += __shfl_xor(s,1); s += __shfl_xor(s,2);
      r256v = s;
    }
    if (w == 0) {                        // corner: R[256][128]
      const int d0 = lane*2;
      float s = z256f[d0]*m1v[d0] + z256f[d0+1]*m1v[d0+1];
      s += __shfl_xor(s,1); s += __shfl_xor(s,2); s += __shfl_xor(s,4);
      s += __shfl_xor(s,8); s += __shfl_xor(s,16); s += __shfl_xor(s,32);
      rcv = s;
    }
    __syncthreads();   // bar E: all z256f/GbB/ZT reads done

    // ===== D-256: update row 256 (f32 state only) =====
    if ((lane & 3) == 0) {
      const int c = tid >> 2;
      float R = r256v*inv_n;
      float z = z256f[c], a = acc256[c], ga = gml[256*129 + c];
      float zn = z + R + a;
      z256f[c] = zn; acc256[c] = a + R*ga;
    }
    if (w == 0 && lane == 0) {
      float R = rcv*inv_n;
      float ga = gml[256*129 + 128];
      float zn = zbar[256] + R + acc256[128];
      zbar[256] = zn; acc256[128] = acc256[128] + R*ga;
    }
  }

  // ---- coalesced f32 output from LDS (overwrites acc scratch region too) ----
  __syncthreads();
  for (int i2 = tid; i2 < 33153; i2 += 512) {
    int r = i2/129, c = i2 - r*129;
    float v;
    if (c < 128) v = (r == 256) ? z256f[c] : bfu(ZT[c*ZTP + r]);
    else         v = zbar[r];
    Zo[i2] = v;
  }
}

// allparam f32 -> bf16, both row-major: Pg[l][i][j]=P[i][j]; Qg[l][i][j]=Q[i][j].
__global__ void prep_params(const float* __restrict__ ap,
                            uint16_t* __restrict__ qg, uint16_t* __restrict__ pg)
{
  int t = blockIdx.x * 256 + threadIdx.x;   // 0..65535 = (l,i,j)
  int l = t >> 14, rem = t & 16383;
  pg[t] = f2bf(ap[(l*2 + 0)*16384 + rem]);
  qg[t] = f2bf(ap[(l*2 + 1)*16384 + rem]);
}

extern "C" void kernel_launch(void* const* d_in, const int* in_sizes, int n_in,
                              void* d_out, int out_size, void* d_ws, size_t ws_size,
                              hipStream_t stream)
{
  const float* Z  = (const float*)d_in[0];
  const float* ap = (const float*)d_in[1];
  const float* gm = (const float*)d_in[2];

  uint16_t* qg = (uint16_t*)d_ws;             // 4*128*128 bf16
  uint16_t* pg = qg + 4*128*128;              // 4*128*128 bf16 (256 KiB total)

  (void)hipFuncSetAttribute((const void*)tf_layers,
                            hipFuncAttributeMaxDynamicSharedMemorySize, LDS_TOTAL);

  prep_params<<<256, 256, 0, stream>>>(ap, qg, pg);
  tf_layers<<<512, 512, LDS_TOTAL, stream>>>(Z, gm, qg, pg, (float*)d_out);
}